// Round 8
// baseline (353.403 us; speedup 1.0000x reference)
//
#include <hip/hip_runtime.h>
#include <hip/hip_bf16.h>

#define VOCAB 2048
#define EMBD  256
#define LATD  64
#define TLEN  32
#define BATCH 64
#define NBLK  256
#define NCG   128   // column groups (16 vocab cols each); rows split 2-way

typedef __attribute__((ext_vector_type(8))) short bf16x8;
typedef __attribute__((ext_vector_type(4))) float f32x4;

// ---------------- init: h ring slot0 = 0, arrv = 0 ----------------
__global__ void k_init(ushort* __restrict__ h0, unsigned* __restrict__ arrv) {
  int i = blockIdx.x * 256 + threadIdx.x;   // grid 512*256 = 131072
  h0[i] = 0;                                 // 64*2048 bf16 (ring slot 0)
  if (i < NBLK) arrv[i] = 0;
}

// ---------- transpose+convert: src[K][8192] f32 -> dst[8192][K] bf16 ----------
__global__ void k_transpose(const float* __restrict__ src,
                            __hip_bfloat16* __restrict__ dst, int K) {
  __shared__ __hip_bfloat16 tile[64][72];
  int k0 = (blockIdx.x >> 7) * 64;
  int n0 = (blockIdx.x & 127) * 64;
  int tid = threadIdx.x;
  {
    int kl = tid >> 2;
    int nq = (tid & 3) << 4;
    const float* s = src + (size_t)(k0 + kl) * 8192 + n0 + nq;
#pragma unroll
    for (int i = 0; i < 4; ++i) {
      float4 v = *reinterpret_cast<const float4*>(s + i * 4);
      tile[nq + i * 4 + 0][kl] = __float2bfloat16(v.x);
      tile[nq + i * 4 + 1][kl] = __float2bfloat16(v.y);
      tile[nq + i * 4 + 2][kl] = __float2bfloat16(v.z);
      tile[nq + i * 4 + 3][kl] = __float2bfloat16(v.w);
    }
  }
  __syncthreads();
  {
    int nl = tid >> 2;
    int kq = (tid & 3) << 4;
    uint4* d = reinterpret_cast<uint4*>(dst + (size_t)(n0 + nl) * K + k0 + kq);
    const uint4* s = reinterpret_cast<const uint4*>(&tile[nl][kq]);
    d[0] = s[0];
    d[1] = s[1];
  }
}

// ---------- gather: xb[t*64+b][256] = bf16(emb[tokens[b][t]]) ----------
__global__ void k_gather(const int* __restrict__ tokens,
                         const float* __restrict__ emb,
                         __hip_bfloat16* __restrict__ xb) {
  int tid = threadIdx.x;
  int row = blockIdx.x * 4 + (tid >> 6);   // 512 blocks -> 2048 rows
  int lane = tid & 63;
  int t = row >> 6, b = row & 63;
  int tok = tokens[b * TLEN + t];
  float4 v = *reinterpret_cast<const float4*>(emb + (size_t)tok * EMBD + lane * 4);
  __hip_bfloat16* d = xb + (size_t)row * EMBD + lane * 4;
  d[0] = __float2bfloat16(v.x);
  d[1] = __float2bfloat16(v.y);
  d[2] = __float2bfloat16(v.z);
  d[3] = __float2bfloat16(v.w);
}

__device__ __forceinline__ void store_agent_u32(unsigned* p, unsigned v) {
  __hip_atomic_store(p, v, __ATOMIC_RELAXED, __HIP_MEMORY_SCOPE_AGENT);
}
__device__ __forceinline__ unsigned long long load_agent_u64(const void* p) {
  return __hip_atomic_load((const unsigned long long*)p, __ATOMIC_RELAXED,
                           __HIP_MEMORY_SCOPE_AGENT);
}
__device__ __forceinline__ void store_agent_f32(float* p, float v) {
  __hip_atomic_store(p, v, __ATOMIC_RELAXED, __HIP_MEMORY_SCOPE_AGENT);
}
__device__ __forceinline__ float2 load_agent_f32x2(const float* p) {
  unsigned long long u = load_agent_u64(p);
  float2 f;
  __builtin_memcpy(&f, &u, 8);
  return f;
}
__device__ __forceinline__ unsigned short bf16_bits(float x) {
  __hip_bfloat16 h = __float2bfloat16(x);
  unsigned short u;
  __builtin_memcpy(&u, &h, 2);
  return u;
}
// Opaque 16B load: compiler can't rematerialize -> value stays in VGPRs.
__device__ __forceinline__ bf16x8 load_opaque(const __hip_bfloat16* p) {
  bf16x8 r;
  asm volatile("global_load_dwordx4 %0, %1, off" : "=&v"(r) : "v"(p));
  return r;
}

// One-hop store-based grid barrier. Each block's wave 0 stores t+1 to its
// own arrv word (parallel, no RMW), then directly polls all 256 words
// (2 x 8B agent loads per lane + __all). Monotone values -> no reset.
// Producers' agent stores (h/stats) are drained by the preceding
// __syncthreads (vmcnt 0) before the arrival store issues.
__device__ __forceinline__ void grid_barrier(unsigned* arrv, int t, int j,
                                             int tid, int lane) {
  __syncthreads();
  const unsigned want = (unsigned)(t + 1);
  if (tid < 64) {                        // wave 0
    if (lane == 0) store_agent_u32(arrv + j, want);
    for (;;) {
      unsigned long long a = load_agent_u64(arrv + 2 * lane);
      unsigned long long b = load_agent_u64(arrv + 128 + 2 * lane);
      bool ok = ((unsigned)a >= want) && ((unsigned)(a >> 32) >= want) &&
                ((unsigned)b >= want) && ((unsigned)(b >> 32) >= want);
      if (__all(ok)) break;
      __builtin_amdgcn_s_sleep(2);
    }
  }
  __syncthreads();
}

// ---------------- persistent kernel: all 32 steps ----------------
// 256 blocks x 512 threads, 1 block/CU. Block j = (cg, rg): cg = j>>1 owns
// vocab cols cg*16..cg*16+15; rg = j&1 owns batch rows rg*32..rg*32+31.
// 8 waves split K=2304 8-ways. B-fragments are loaded ONCE via opaque asm
// loads (144 VGPRs, unspillable-by-remat) -> zero weight traffic in t-loop.
// A-loads run a depth-3 register ring to cover LLC first-touch latency.
__global__ __launch_bounds__(512, 1) void k_persist(
    const int* __restrict__ tokens,
    const __hip_bfloat16* __restrict__ WhT,   // [8192][2048]
    const __hip_bfloat16* __restrict__ WxT,   // [8192][256]
    const __hip_bfloat16* __restrict__ xb,    // [2048][256] row = t*64+b
    const float* __restrict__ bias,           // [8192]
    __hip_bfloat16* __restrict__ hring,       // [33][64][2048]
    float* __restrict__ stats,                // [2][3][64][128]
    float* __restrict__ out,                  // [64][32][64]
    unsigned* __restrict__ arrv) {            // [256]
  const int tid = threadIdx.x;
  const int lane = tid & 63;
  const int wid = tid >> 6;                  // 0..7 = K-split
  const int j = blockIdx.x;
  const int cg = j >> 1;                     // column group 0..127
  const int rg = j & 1;                      // row group 0..1
  const int r0 = rg << 5;                    // first batch row

  __shared__ float racc[8][2][4][4][64];   // [wid][mf][gt][r][lane] 64KB
  __shared__ float sval[TLEN];

  const int rr = lane & 15;
  const int kg = lane >> 4;                 // 0..3 (K groups of 8)

  // ---- preload B fragments via opaque loads (144 VGPRs, loop-invariant) ----
  bf16x8 Bf[9][4];
#pragma unroll
  for (int it = 0; it < 8; ++it) {
    int kb = (wid * 8 + it) * 32 + kg * 8;
#pragma unroll
    for (int gt = 0; gt < 4; ++gt)
      Bf[it][gt] = load_opaque(WhT + (size_t)((gt << 11) + (cg << 4) + rr) * VOCAB + kb);
  }
  {
    int kx = wid * 32 + kg * 8;
#pragma unroll
    for (int gt = 0; gt < 4; ++gt)
      Bf[8][gt] = load_opaque(WxT + (size_t)((gt << 11) + (cg << 4) + rr) * EMBD + kx);
  }
  asm volatile("s_waitcnt vmcnt(0)" ::: "memory");
  __builtin_amdgcn_sched_barrier(0);

  // ---- epilogue constants: this thread owns cell (rowg, v) ----
  const int m_e = wid >> 2;                 // 0..1
  const int r_e = wid & 3;                  // 0..3
  const int rowg = r0 + m_e * 16 + kg * 4 + r_e;   // global batch row
  const int v = (cg << 4) + rr;             // global vocab col
  float bias_r[4];
#pragma unroll
  for (int gt = 0; gt < 4; ++gt) bias_r[gt] = bias[gt * 2048 + v];
  float c_reg = 0.f;

  for (int t = 0; t < TLEN; ++t) {
    const int par = t & 1;
    const __hip_bfloat16* hcur = hring + (size_t)t * (BATCH * VOCAB);
    __hip_bfloat16* hnext = (__hip_bfloat16*)hring + (size_t)(t + 1) * (BATCH * VOCAB);
    const int tnext = (t + 1 < TLEN) ? t + 1 : TLEN - 1;
    const int tok = tokens[rowg * TLEN + tnext];

    // ---- bounds value for step t -> sval[t] (wave 0 of blocks j<64) ----
    if (j < BATCH && wid == 0) {
      float val;
      if (t == 0) {
        int tk = tokens[j * TLEN];
        val = 1.5f * (2.f * tk + 1.f) * (1.f / 2048.f);
      } else {
        const float* st = stats + par * 3 * BATCH * NCG;
        float2 u0 = load_agent_f32x2(st + (0 * BATCH + j) * NCG + lane * 2);
        float2 u1 = load_agent_f32x2(st + (1 * BATCH + j) * NCG + lane * 2);
        float2 u2 = load_agent_f32x2(st + (2 * BATCH + j) * NCG + lane * 2);
        float a0 = u0.x + u0.y, a1 = u1.x + u1.y, a2 = u2.x + u2.y;
#pragma unroll
        for (int mm = 1; mm <= 32; mm <<= 1) {
          a0 += __shfl_xor(a0, mm);
          a1 += __shfl_xor(a1, mm);
          a2 += __shfl_xor(a2, mm);
        }
        val = 1.5f * (2.f * a1 + a2) / a0;
      }
      if (lane == t) sval[t] = val;
    }

    // ---- GEMM: z[32 rows x 64 zcols] over K=2304, 8 waves split K ----
    f32x4 acc[2][4];
#pragma unroll
    for (int mf = 0; mf < 2; ++mf)
#pragma unroll
      for (int gt = 0; gt < 4; ++gt) acc[mf][gt] = (f32x4){0.f, 0.f, 0.f, 0.f};

    const __hip_bfloat16* aBase = hcur + (size_t)(r0 + rr) * VOCAB + wid * 256 + kg * 8;
    const __hip_bfloat16* xBase = xb + (size_t)t * BATCH * EMBD +
                                  (size_t)(r0 + rr) * EMBD + wid * 32 + kg * 8;
    bf16x8 Ar[3][2];
    auto issue = [&](int it) {
      int slot = it % 3;
      if (it < 8) {
        Ar[slot][0] = *(const bf16x8*)(aBase + it * 32);
        Ar[slot][1] = *(const bf16x8*)(aBase + 16 * VOCAB + it * 32);
      } else {
        Ar[slot][0] = *(const bf16x8*)(xBase);
        Ar[slot][1] = *(const bf16x8*)(xBase + 16 * EMBD);
      }
    };

#pragma unroll
    for (int it = 0; it < 3; ++it) issue(it);
#pragma unroll
    for (int it = 0; it < 9; ++it) {
      const int sl = it % 3;
#pragma unroll
      for (int gt = 0; gt < 4; ++gt) {
        acc[0][gt] = __builtin_amdgcn_mfma_f32_16x16x32_bf16(Ar[sl][0], Bf[it][gt], acc[0][gt], 0, 0, 0);
        acc[1][gt] = __builtin_amdgcn_mfma_f32_16x16x32_bf16(Ar[sl][1], Bf[it][gt], acc[1][gt], 0, 0, 0);
      }
      if (it + 3 < 9) issue(it + 3);
    }

    // ---- cross-wave K reduction ----
#pragma unroll
    for (int mf = 0; mf < 2; ++mf)
#pragma unroll
      for (int gt = 0; gt < 4; ++gt)
#pragma unroll
        for (int r = 0; r < 4; ++r) racc[wid][mf][gt][r][lane] = acc[mf][gt][r];
    __syncthreads();

    // ---- epilogue: one cell per thread; all 4 gates from LDS ----
    float z[4];
#pragma unroll
    for (int gt = 0; gt < 4; ++gt) {
      float s = bias_r[gt];
#pragma unroll
      for (int w = 0; w < 8; ++w) s += racc[w][m_e][gt][r_e][lane];
      z[gt] = s;
    }
    float gi = 1.f / (1.f + __expf(-z[0]));
    float gf = 1.f / (1.f + __expf(-z[1]));
    float go = 1.f / (1.f + __expf(-z[3]));
    float cnew = gf * c_reg + gi * tanhf(z[2]);
    float hn = go * tanhf(cnew);
    c_reg = cnew;

    // h store: pack col pairs -> one u32 agent store (LLC) per even lane
    {
      unsigned b0 = bf16_bits(hn);
      unsigned q0 = (unsigned)__shfl_xor((int)b0, 1);
      if (!(rr & 1))
        store_agent_u32((unsigned*)(hnext + rowg * VOCAB + v), b0 | (q0 << 16));
    }

    // stats partials over this block's 16 cols (reduce within 16-lane group)
    float e = __expf(hn);
    float sl = (v < tok) ? e : 0.f;
    float st = (v == tok) ? e : 0.f;
#pragma unroll
    for (int mm = 1; mm <= 8; mm <<= 1) {
      e += __shfl_xor(e, mm);
      sl += __shfl_xor(sl, mm);
      st += __shfl_xor(st, mm);
    }
    if (rr == 0) {
      float* stn = stats + (par ^ 1) * 3 * BATCH * NCG;
      store_agent_f32(&stn[(0 * BATCH + rowg) * NCG + cg], e);
      store_agent_f32(&stn[(1 * BATCH + rowg) * NCG + cg], sl);
      store_agent_f32(&stn[(2 * BATCH + rowg) * NCG + cg], st);
    }

    if (t < TLEN - 1) grid_barrier(arrv, t, j, tid, lane);
  }

  // ---- write out[j] once: d<=t' -> sval[d], else 1.5 (initial bounds) ----
  if (j < BATCH) {
    __syncthreads();
    for (int idx = tid; idx < TLEN * LATD; idx += 512) {
      int tp = idx >> 6, d = idx & 63;
      out[j * TLEN * LATD + idx] = (d < TLEN && d <= tp) ? sval[d] : 1.5f;
    }
  }
}

extern "C" void kernel_launch(void* const* d_in, const int* in_sizes, int n_in,
                              void* d_out, int out_size, void* d_ws, size_t ws_size,
                              hipStream_t stream) {
  (void)in_sizes; (void)n_in; (void)out_size; (void)ws_size;
  const int* tokens = (const int*)d_in[0];
  const float* emb  = (const float*)d_in[1];
  const float* Wx   = (const float*)d_in[2];
  const float* Wh   = (const float*)d_in[3];
  const float* bias = (const float*)d_in[4];
  float* out = (float*)d_out;
  char* ws = (char*)d_ws;

  __hip_bfloat16* WhT = (__hip_bfloat16*)(ws);               // 33,554,432 B
  __hip_bfloat16* WxT = (__hip_bfloat16*)(ws + 33554432);    //  4,194,304 B
  __hip_bfloat16* xb  = (__hip_bfloat16*)(ws + 37748736);    //  1,048,576 B
  __hip_bfloat16* hr  = (__hip_bfloat16*)(ws + 38797312);    //  8,650,752 B (33 slots)
  float* stats        = (float*)(ws + 47448064);             //    196,608 B
  unsigned* arrv      = (unsigned*)(ws + 47644672);          //      1,024 B

  k_init<<<512, 256, 0, stream>>>((ushort*)hr, arrv);
  k_transpose<<<4096, 256, 0, stream>>>(Wh, WhT, 2048);
  k_transpose<<<512, 256, 0, stream>>>(Wx, WxT, 256);
  k_gather<<<512, 256, 0, stream>>>(tokens, emb, xb);
  k_persist<<<NBLK, 512, 0, stream>>>(tokens, WhT, WxT, xb, bias, hr, stats, out, arrv);
}

// Round 10
// 270.247 us; speedup vs baseline: 1.3077x; 1.3077x over previous
//
#include <hip/hip_runtime.h>
#include <hip/hip_bf16.h>

#define VOCAB 2048
#define EMBD  256
#define LATD  64
#define TLEN  32
#define BATCH 64
#define NBLK  256
#define NCG   128   // column groups (16 vocab cols each); rows split 2-way

typedef __attribute__((ext_vector_type(8))) short bf16x8;
typedef __attribute__((ext_vector_type(4))) float f32x4;

// ---------------- init: h ring slot0 = 0, arrv/rel = 0 ----------------
__global__ void k_init(ushort* __restrict__ h0, unsigned* __restrict__ arrv) {
  int i = blockIdx.x * 256 + threadIdx.x;   // grid 512*256 = 131072
  h0[i] = 0;                                 // 64*2048 bf16 (ring slot 0)
  if (i < 384) arrv[i] = 0;                  // 256 arrv + 128 rel words
}

// ---------- transpose+convert: src[K][8192] f32 -> dst[8192][K] bf16 ----------
__global__ void k_transpose(const float* __restrict__ src,
                            __hip_bfloat16* __restrict__ dst, int K) {
  __shared__ __hip_bfloat16 tile[64][72];
  int k0 = (blockIdx.x >> 7) * 64;
  int n0 = (blockIdx.x & 127) * 64;
  int tid = threadIdx.x;
  {
    int kl = tid >> 2;
    int nq = (tid & 3) << 4;
    const float* s = src + (size_t)(k0 + kl) * 8192 + n0 + nq;
#pragma unroll
    for (int i = 0; i < 4; ++i) {
      float4 v = *reinterpret_cast<const float4*>(s + i * 4);
      tile[nq + i * 4 + 0][kl] = __float2bfloat16(v.x);
      tile[nq + i * 4 + 1][kl] = __float2bfloat16(v.y);
      tile[nq + i * 4 + 2][kl] = __float2bfloat16(v.z);
      tile[nq + i * 4 + 3][kl] = __float2bfloat16(v.w);
    }
  }
  __syncthreads();
  {
    int nl = tid >> 2;
    int kq = (tid & 3) << 4;
    uint4* d = reinterpret_cast<uint4*>(dst + (size_t)(n0 + nl) * K + k0 + kq);
    const uint4* s = reinterpret_cast<const uint4*>(&tile[nl][kq]);
    d[0] = s[0];
    d[1] = s[1];
  }
}

// ---------- gather: xb[t*64+b][256] = bf16(emb[tokens[b][t]]) ----------
__global__ void k_gather(const int* __restrict__ tokens,
                         const float* __restrict__ emb,
                         __hip_bfloat16* __restrict__ xb) {
  int tid = threadIdx.x;
  int row = blockIdx.x * 4 + (tid >> 6);   // 512 blocks -> 2048 rows
  int lane = tid & 63;
  int t = row >> 6, b = row & 63;
  int tok = tokens[b * TLEN + t];
  float4 v = *reinterpret_cast<const float4*>(emb + (size_t)tok * EMBD + lane * 4);
  __hip_bfloat16* d = xb + (size_t)row * EMBD + lane * 4;
  d[0] = __float2bfloat16(v.x);
  d[1] = __float2bfloat16(v.y);
  d[2] = __float2bfloat16(v.z);
  d[3] = __float2bfloat16(v.w);
}

__device__ __forceinline__ void store_agent_u32(unsigned* p, unsigned v) {
  __hip_atomic_store(p, v, __ATOMIC_RELAXED, __HIP_MEMORY_SCOPE_AGENT);
}
__device__ __forceinline__ unsigned load_agent_u32(const unsigned* p) {
  return __hip_atomic_load(p, __ATOMIC_RELAXED, __HIP_MEMORY_SCOPE_AGENT);
}
__device__ __forceinline__ unsigned long long load_agent_u64(const void* p) {
  return __hip_atomic_load((const unsigned long long*)p, __ATOMIC_RELAXED,
                           __HIP_MEMORY_SCOPE_AGENT);
}
__device__ __forceinline__ void store_agent_f32(float* p, float v) {
  __hip_atomic_store(p, v, __ATOMIC_RELAXED, __HIP_MEMORY_SCOPE_AGENT);
}
__device__ __forceinline__ float2 load_agent_f32x2(const float* p) {
  unsigned long long u = load_agent_u64(p);
  float2 f;
  __builtin_memcpy(&f, &u, 8);
  return f;
}
__device__ __forceinline__ unsigned short bf16_bits(float x) {
  __hip_bfloat16 h = __float2bfloat16(x);
  unsigned short u;
  __builtin_memcpy(&u, &h, 2);
  return u;
}

// Two-hop store-based grid barrier (round-7 design, best measured).
// Arrival: each block STORES t+1 into its own arrv word (no RMW). Block 0's
// wave 0 polls all 256 words (2 x 8B agent loads/lane + __all), then stores
// 8 per-XCD release lines; other blocks poll their release line only.
// Monotone values -> no reset. Producers' agent stores (h/stats) are drained
// by the preceding __syncthreads (vmcnt 0) before the arrival store issues.
__device__ __forceinline__ void grid_barrier(unsigned* arrv, unsigned* rel,
                                             int t, int j, int tid, int lane) {
  __syncthreads();
  const unsigned want = (unsigned)(t + 1);
  if (j == 0) {
    if (tid < 64) {                      // wave 0
      if (lane == 0) store_agent_u32(arrv, want);
      for (;;) {
        unsigned long long a = load_agent_u64(arrv + 2 * lane);
        unsigned long long b = load_agent_u64(arrv + 128 + 2 * lane);
        bool ok = ((unsigned)a >= want) && ((unsigned)(a >> 32) >= want) &&
                  ((unsigned)b >= want) && ((unsigned)(b >> 32) >= want);
        if (__all(ok)) break;
      }
      if (lane < 8) store_agent_u32(rel + (lane << 4), want);
    }
  } else {
    if (tid == 0) {
      store_agent_u32(arrv + j, want);
      while (load_agent_u32(rel + ((j & 7) << 4)) < want)
        __builtin_amdgcn_s_sleep(1);
    }
  }
  __syncthreads();
}

// ---------------- persistent kernel: all 32 steps ----------------
// 256 blocks x 512 threads. XCD-swizzled work split: cg=(j&7)|((j>>4)<<3),
// rg=(j>>3)&1 -> the two rg-blocks of a cg share j%8 (same XCD) so their
// common B panel is fetched once per XCD into L2. 8 waves split K=2304.
// A and B both run depth-4 register rings (24 loads in flight) so L2/LLC
// latency hides under MFMA. Bounds-calc is distributed over waves 0..2 and
// deferred (combine at the final out-write).
__global__ __launch_bounds__(512, 1) void k_persist(
    const int* __restrict__ tokens,
    const __hip_bfloat16* __restrict__ WhT,   // [8192][2048]
    const __hip_bfloat16* __restrict__ WxT,   // [8192][256]
    const __hip_bfloat16* __restrict__ xb,    // [2048][256] row = t*64+b
    const float* __restrict__ bias,           // [8192]
    __hip_bfloat16* __restrict__ hring,       // [33][64][2048]
    float* __restrict__ stats,                // [2][3][64][128]
    float* __restrict__ out,                  // [64][32][64]
    unsigned* __restrict__ arrv,              // [256]
    unsigned* __restrict__ rel) {             // [8*16]
  const int tid = threadIdx.x;
  const int lane = tid & 63;
  const int wid = tid >> 6;                  // 0..7 = K-split
  const int j = blockIdx.x;                  // physical id (barrier, bounds)
  const int cg = (j & 7) | ((j >> 4) << 3);  // column group 0..127 (swizzled)
  const int rg = (j >> 3) & 1;               // row group 0..1
  const int r0 = rg << 5;                    // first batch row

  __shared__ float racc[8][2][4][4][64];   // [wid][mf][gt][r][lane] 64KB
  __shared__ float spart[TLEN][3];         // deferred bounds partials
  __shared__ float sval[TLEN];

  const int rr = lane & 15;
  const int kg = lane >> 4;                 // 0..3 (K-subgroups of 8)

  // ---- loop-invariant base pointers ----
  const __hip_bfloat16* bBase[4];
#pragma unroll
  for (int gt = 0; gt < 4; ++gt)
    bBase[gt] = WhT + (size_t)((gt << 11) + (cg << 4) + rr) * VOCAB + wid * 256 + kg * 8;
  const __hip_bfloat16* bxBase[4];
#pragma unroll
  for (int gt = 0; gt < 4; ++gt)
    bxBase[gt] = WxT + (size_t)((gt << 11) + (cg << 4) + rr) * EMBD + wid * 32 + kg * 8;

  // ---- epilogue constants: this thread owns cell (rowg, v) ----
  const int m_e = wid >> 2;                 // 0..1
  const int r_e = wid & 3;                  // 0..3
  const int rowg = r0 + m_e * 16 + kg * 4 + r_e;   // global batch row
  const int v = (cg << 4) + rr;             // global vocab col
  float bias_r[4];
#pragma unroll
  for (int gt = 0; gt < 4; ++gt) bias_r[gt] = bias[gt * 2048 + v];
  float c_reg = 0.f;

  for (int t = 0; t < TLEN; ++t) {
    const int par = t & 1;
    const __hip_bfloat16* hcur = hring + (size_t)t * (BATCH * VOCAB);
    __hip_bfloat16* hnext = (__hip_bfloat16*)hring + (size_t)(t + 1) * (BATCH * VOCAB);
    const int tnext = (t + 1 < TLEN) ? t + 1 : TLEN - 1;
    const int tok = tokens[rowg * TLEN + tnext];

    // ---- distributed bounds load: waves 0..2 of blocks j<64, 1x8B each ----
    float2 sv;
    const bool do_stat = (t > 0) && (j < BATCH) && (wid < 3);
    if (do_stat)
      sv = load_agent_f32x2(stats + par * 3 * BATCH * NCG +
                            (wid * BATCH + j) * NCG + lane * 2);

    // ---- GEMM: z[32 rows x 64 zcols] over K=2304, 8 waves split K ----
    f32x4 acc[2][4];
#pragma unroll
    for (int mf = 0; mf < 2; ++mf)
#pragma unroll
      for (int gt = 0; gt < 4; ++gt) acc[mf][gt] = (f32x4){0.f, 0.f, 0.f, 0.f};

    const __hip_bfloat16* aBase = hcur + (size_t)(r0 + rr) * VOCAB + wid * 256 + kg * 8;
    const __hip_bfloat16* xBase = xb + (size_t)t * BATCH * EMBD +
                                  (size_t)(r0 + rr) * EMBD + wid * 32 + kg * 8;
    bf16x8 Ar[4][2];
    bf16x8 Br[4][4];
    auto issue = [&](int it) {
      int slot = it & 3;
      if (it < 8) {
        Ar[slot][0] = *(const bf16x8*)(aBase + it * 32);
        Ar[slot][1] = *(const bf16x8*)(aBase + 16 * VOCAB + it * 32);
#pragma unroll
        for (int gt = 0; gt < 4; ++gt)
          Br[slot][gt] = *(const bf16x8*)(bBase[gt] + it * 32);
      } else {
        Ar[slot][0] = *(const bf16x8*)(xBase);
        Ar[slot][1] = *(const bf16x8*)(xBase + 16 * EMBD);
#pragma unroll
        for (int gt = 0; gt < 4; ++gt)
          Br[slot][gt] = *(const bf16x8*)(bxBase[gt]);
      }
    };

#pragma unroll
    for (int it = 0; it < 4; ++it) issue(it);
#pragma unroll
    for (int it = 0; it < 9; ++it) {
      const int sl = it & 3;
#pragma unroll
      for (int gt = 0; gt < 4; ++gt) {
        acc[0][gt] = __builtin_amdgcn_mfma_f32_16x16x32_bf16(Ar[sl][0], Br[sl][gt], acc[0][gt], 0, 0, 0);
        acc[1][gt] = __builtin_amdgcn_mfma_f32_16x16x32_bf16(Ar[sl][1], Br[sl][gt], acc[1][gt], 0, 0, 0);
      }
      if (it + 4 < 9) issue(it + 4);
    }

    // ---- cross-wave K reduction ----
#pragma unroll
    for (int mf = 0; mf < 2; ++mf)
#pragma unroll
      for (int gt = 0; gt < 4; ++gt)
#pragma unroll
        for (int r = 0; r < 4; ++r) racc[wid][mf][gt][r][lane] = acc[mf][gt][r];
    __syncthreads();

    // ---- deferred bounds partial: reduce sv across wave, park in LDS ----
    if (do_stat) {
      float a = sv.x + sv.y;
#pragma unroll
      for (int mm = 1; mm <= 32; mm <<= 1) a += __shfl_xor(a, mm);
      if (lane == 0) spart[t][wid] = a;
    }

    // ---- epilogue: one cell per thread; all 4 gates from LDS ----
    float z[4];
#pragma unroll
    for (int gt = 0; gt < 4; ++gt) {
      float s = bias_r[gt];
#pragma unroll
      for (int w = 0; w < 8; ++w) s += racc[w][m_e][gt][r_e][lane];
      z[gt] = s;
    }
    float gi = 1.f / (1.f + __expf(-z[0]));
    float gf = 1.f / (1.f + __expf(-z[1]));
    float go = 1.f / (1.f + __expf(-z[3]));
    float cnew = gf * c_reg + gi * tanhf(z[2]);
    float hn = go * tanhf(cnew);
    c_reg = cnew;

    // h store: pack col pairs -> one u32 agent store (LLC) per even lane
    {
      unsigned b0 = bf16_bits(hn);
      unsigned q0 = (unsigned)__shfl_xor((int)b0, 1);
      if (!(rr & 1))
        store_agent_u32((unsigned*)(hnext + rowg * VOCAB + v), b0 | (q0 << 16));
    }

    // stats partials over this block's 16 cols (reduce within 16-lane group)
    float e = __expf(hn);
    float sl = (v < tok) ? e : 0.f;
    float st = (v == tok) ? e : 0.f;
#pragma unroll
    for (int mm = 1; mm <= 8; mm <<= 1) {
      e += __shfl_xor(e, mm);
      sl += __shfl_xor(sl, mm);
      st += __shfl_xor(st, mm);
    }
    if (rr == 0) {
      float* stn = stats + (par ^ 1) * 3 * BATCH * NCG;
      store_agent_f32(&stn[(0 * BATCH + rowg) * NCG + cg], e);
      store_agent_f32(&stn[(1 * BATCH + rowg) * NCG + cg], sl);
      store_agent_f32(&stn[(2 * BATCH + rowg) * NCG + cg], st);
    }

    if (t < TLEN - 1) grid_barrier(arrv, rel, t, j, tid, lane);
  }

  // ---- finalize bounds + write out[j] (blocks j<64 only) ----
  if (j < BATCH) {
    __syncthreads();                       // spart of step 31 visible
    if (tid < TLEN) {
      float val;
      if (tid == 0) {
        int tk = tokens[j * TLEN];
        val = 1.5f * (2.f * tk + 1.f) * (1.f / 2048.f);
      } else {
        float S  = spart[tid][0];
        float SL = spart[tid][1];
        float ST = spart[tid][2];
        val = 1.5f * (2.f * SL + ST) / S;
      }
      sval[tid] = val;
    }
    __syncthreads();
    for (int idx = tid; idx < TLEN * LATD; idx += 512) {
      int tp = idx >> 6, d = idx & 63;
      out[j * TLEN * LATD + idx] = (d < TLEN && d <= tp) ? sval[d] : 1.5f;
    }
  }
}

extern "C" void kernel_launch(void* const* d_in, const int* in_sizes, int n_in,
                              void* d_out, int out_size, void* d_ws, size_t ws_size,
                              hipStream_t stream) {
  (void)in_sizes; (void)n_in; (void)out_size; (void)ws_size;
  const int* tokens = (const int*)d_in[0];
  const float* emb  = (const float*)d_in[1];
  const float* Wx   = (const float*)d_in[2];
  const float* Wh   = (const float*)d_in[3];
  const float* bias = (const float*)d_in[4];
  float* out = (float*)d_out;
  char* ws = (char*)d_ws;

  __hip_bfloat16* WhT = (__hip_bfloat16*)(ws);               // 33,554,432 B
  __hip_bfloat16* WxT = (__hip_bfloat16*)(ws + 33554432);    //  4,194,304 B
  __hip_bfloat16* xb  = (__hip_bfloat16*)(ws + 37748736);    //  1,048,576 B
  __hip_bfloat16* hr  = (__hip_bfloat16*)(ws + 38797312);    //  8,650,752 B (33 slots)
  float* stats        = (float*)(ws + 47448064);             //    196,608 B
  unsigned* arrv      = (unsigned*)(ws + 47644672);          //      1,024 B
  unsigned* rel       = (unsigned*)(ws + 47645696);          //        512 B

  k_init<<<512, 256, 0, stream>>>((ushort*)hr, arrv);
  k_transpose<<<4096, 256, 0, stream>>>(Wh, WhT, 2048);
  k_transpose<<<512, 256, 0, stream>>>(Wx, WxT, 256);
  k_gather<<<512, 256, 0, stream>>>(tokens, emb, xb);
  k_persist<<<NBLK, 512, 0, stream>>>(tokens, WhT, WxT, xb, bias, hr, stats, out, arrv, rel);
}